// Round 1
// baseline (71.045 us; speedup 1.0000x reference)
//
#include <hip/hip_runtime.h>
#include <math.h>

#define W48 48
#define HD 2304      // 48*48
#define WHD 110592   // 48^3
#define NR 32
#define NB 8
#define NPLANES 256      // NB*NR
#define QPP 27648        // WHD/4 float4 groups per plane
#define K2_BLOCKS 864    // NB*QPP/256
#define NTOT 28311552.0  // NB*NR*WHD

struct PlaneRes {
  double s0, sx, sy, sii, ssum;
  int am;
  int pad;
};

// ---------------- Kernel 1: per-(b,r) plane moments + argmax ----------------
__global__ __launch_bounds__(256)
void k_plane(const float* __restrict__ feat, PlaneRes* __restrict__ pres) {
  const int plane = blockIdx.x;   // b*32 + r
  const int t = threadIdx.x;
  const float4* f4 = reinterpret_cast<const float4*>(feat + (size_t)plane * WHD);

  float maxv = -INFINITY; int maxi = 0;
  float s0 = 0.f, sx = 0.f, sy = 0.f, sii = 0.f, ssum = 0.f;

  for (int q = t; q < QPP; q += 256) {
    float4 v = f4[q];
    float vv[4] = {v.x, v.y, v.z, v.w};
    int p0 = q * 4;
#pragma unroll
    for (int c = 0; c < 4; ++c) {
      float f = vv[c];
      int p = p0 + c;
      int i = p / HD;
      int rem = p - i * HD;
      int j = rem / W48;
      float f2 = f * f;
      float fi = (float)i, fj = (float)j;
      s0  += f2;
      sx  += f2 * fi;
      sy  += f2 * fj;
      sii += f2 * (fi * fi + fj * fj);
      ssum += f;
      if (f > maxv) { maxv = f; maxi = p; }   // strict > : first-index tie-break
    }
  }

  double d0 = s0, d1 = sx, d2 = sy, d3 = sii, d4 = ssum;
#pragma unroll
  for (int off = 32; off > 0; off >>= 1) {
    float ov = __shfl_down(maxv, off);
    int   oi = __shfl_down(maxi, off);
    if (ov > maxv || (ov == maxv && oi < maxi)) { maxv = ov; maxi = oi; }
    d0 += __shfl_down(d0, off);
    d1 += __shfl_down(d1, off);
    d2 += __shfl_down(d2, off);
    d3 += __shfl_down(d3, off);
    d4 += __shfl_down(d4, off);
  }

  __shared__ double ls[4][5];
  __shared__ float  lmax[4];
  __shared__ int    lidx[4];
  int wave = t >> 6, lane = t & 63;
  if (lane == 0) {
    ls[wave][0] = d0; ls[wave][1] = d1; ls[wave][2] = d2;
    ls[wave][3] = d3; ls[wave][4] = d4;
    lmax[wave] = maxv; lidx[wave] = maxi;
  }
  __syncthreads();
  if (t == 0) {
    double a0=0, a1=0, a2=0, a3=0, a4=0;
    float mv = -INFINITY; int mi = 0;
#pragma unroll
    for (int w = 0; w < 4; ++w) {
      a0 += ls[w][0]; a1 += ls[w][1]; a2 += ls[w][2]; a3 += ls[w][3]; a4 += ls[w][4];
      if (lmax[w] > mv || (lmax[w] == mv && lidx[w] < mi)) { mv = lmax[w]; mi = lidx[w]; }
    }
    PlaneRes r; r.s0=a0; r.sx=a1; r.sy=a2; r.sii=a3; r.ssum=a4; r.am=mi; r.pad=0;
    pres[plane] = r;
  }
}

// ------- Kernel 2: per-(b,pos) max / second-max over r  ->  A,B,C sums -------
__global__ __launch_bounds__(256)
void k_div(const float* __restrict__ feat, double* __restrict__ blk) {
  const unsigned gid = blockIdx.x * 256u + threadIdx.x;
  const unsigned b = gid / QPP;
  const unsigned q = gid - b * QPP;
  const float4* base = reinterpret_cast<const float4*>(feat + (size_t)b * NR * WHD) + q;

  float v1[4], v2[4], f2m[4], cp[4];
#pragma unroll
  for (int c = 0; c < 4; ++c) { v1[c] = -INFINITY; v2[c] = -INFINITY; f2m[c] = 0.f; cp[c] = 0.f; }

#pragma unroll 4
  for (int r = 0; r < NR; ++r) {
    float4 v = base[(size_t)r * QPP];
    float vv[4] = {v.x, v.y, v.z, v.w};
#pragma unroll
    for (int c = 0; c < 4; ++c) {
      float f = vv[c], f2 = f * f;
      cp[c] += f2;
      if (f > v1[c]) { v2[c] = v1[c]; v1[c] = f; f2m[c] = f2; }  // first-index tie-break
      else if (f > v2[c]) { v2[c] = f; }
    }
  }

  float A = 0.f, Bs = 0.f, C = 0.f;
#pragma unroll
  for (int c = 0; c < 4; ++c) {
    float rest = cp[c] - f2m[c];
    A  += v1[c] * v1[c] * rest + v2[c] * v2[c] * f2m[c];
    Bs += v1[c] * rest + v2[c] * f2m[c];
    C  += cp[c];
  }

  double dA = A, dB = Bs, dC = C;
#pragma unroll
  for (int off = 32; off > 0; off >>= 1) {
    dA += __shfl_down(dA, off);
    dB += __shfl_down(dB, off);
    dC += __shfl_down(dC, off);
  }
  __shared__ double ls[4][3];
  int wave = threadIdx.x >> 6, lane = threadIdx.x & 63;
  if (lane == 0) { ls[wave][0] = dA; ls[wave][1] = dB; ls[wave][2] = dC; }
  __syncthreads();
  if (threadIdx.x == 0) {
    double a = 0, bb = 0, cc = 0;
#pragma unroll
    for (int w = 0; w < 4; ++w) { a += ls[w][0]; bb += ls[w][1]; cc += ls[w][2]; }
    blk[blockIdx.x * 3 + 0] = a;
    blk[blockIdx.x * 3 + 1] = bb;
    blk[blockIdx.x * 3 + 2] = cc;
  }
}

// ---------------------------- Kernel 3: finalize ----------------------------
__global__ __launch_bounds__(256)
void k_final(const PlaneRes* __restrict__ pres, const double* __restrict__ blk,
             float* __restrict__ out) {
  const int t = threadIdx.x;

  PlaneRes pr = pres[t];            // exactly 256 planes, one per thread
  int am = pr.am;
  int mx = am / HD;
  int rem = am - mx * HD;
  int my = rem / W48;
  int mz = rem - my * W48;
  double dmx = mx, dmy = my, dmz = mz;
  // sum_k (mz-k)^2 for k=0..47 = 48*mz^2 - 2*1128*mz + 35720 ; times W*H=2304
  double dis = (dmx*dmx + dmy*dmy) * pr.s0 - 2.0*dmx*pr.sx - 2.0*dmy*pr.sy + pr.sii
             + 2304.0 * (48.0*dmz*dmz - 2256.0*dmz + 35720.0);
  double ssum = pr.ssum;

  double A = 0, Bs = 0, C = 0;
  for (int idx = t; idx < K2_BLOCKS; idx += 256) {
    A  += blk[idx * 3 + 0];
    Bs += blk[idx * 3 + 1];
    C  += blk[idx * 3 + 2];
  }

#pragma unroll
  for (int off = 32; off > 0; off >>= 1) {
    dis  += __shfl_down(dis, off);
    ssum += __shfl_down(ssum, off);
    A    += __shfl_down(A, off);
    Bs   += __shfl_down(Bs, off);
    C    += __shfl_down(C, off);
  }
  __shared__ double ls[4][5];
  int wave = t >> 6, lane = t & 63;
  if (lane == 0) {
    ls[wave][0] = dis; ls[wave][1] = ssum; ls[wave][2] = A; ls[wave][3] = Bs; ls[wave][4] = C;
  }
  __syncthreads();
  if (t == 0) {
    double td = 0, ts = 0, tA = 0, tB = 0, tC = 0;
#pragma unroll
    for (int w = 0; w < 4; ++w) {
      td += ls[w][0]; ts += ls[w][1]; tA += ls[w][2]; tB += ls[w][3]; tC += ls[w][4];
    }
    double mgr = ts / NTOT;
    out[0] = (float)(td / NTOT);
    out[1] = (float)((tA - 2.0 * mgr * tB + mgr * mgr * tC) / NTOT);
  }
}

extern "C" void kernel_launch(void* const* d_in, const int* in_sizes, int n_in,
                              void* d_out, int out_size, void* d_ws, size_t ws_size,
                              hipStream_t stream) {
  // inputs: [0]=backbone_feature (unused), [1]=grouping_result (unused), [2]=feature
  const float* feat = (const float*)d_in[2];
  float* out = (float*)d_out;

  PlaneRes* pres = (PlaneRes*)d_ws;                                   // 256*48 = 12288 B
  double* blk = (double*)((char*)d_ws + sizeof(PlaneRes) * NPLANES);  // 864*3*8 = 20736 B

  k_plane<<<NPLANES, 256, 0, stream>>>(feat, pres);
  k_div<<<K2_BLOCKS, 256, 0, stream>>>(feat, blk);
  k_final<<<1, 256, 0, stream>>>(pres, blk, out);
}

// Round 2
// 48.000 us; speedup vs baseline: 1.4801x; 1.4801x over previous
//
#include <hip/hip_runtime.h>
#include <math.h>

#define W48 48
#define HD 2304      // 48*48
#define WHD 110592   // 48^3
#define NR 32
#define NB 8
#define NPLANES 256       // NB*NR
#define QPP 27648         // WHD/4 float4 groups per plane
#define PLANE_SUBS 12     // sub-blocks per plane
#define QSUB 2304         // QPP/12 groups per sub-block (= 9 iters of 256)
#define PLANE_BLOCKS 3072 // NPLANES*PLANE_SUBS
#define DIV_BLOCKS 864    // NB*QPP/256
#define NTOT 28311552.0   // NB*NR*WHD

struct PlanePart {
  double s0, sx, sy, sii, ssum;
  float maxv;
  int maxi;
};  // 48 B

// ---------------- fused kernel: div path (blocks [0,864)) + plane path ------
__global__ __launch_bounds__(256)
void k_main(const float* __restrict__ feat, PlanePart* __restrict__ pp,
            double* __restrict__ blk) {
  const int bid = blockIdx.x;
  const int t = threadIdx.x;

  __shared__ double ls[4][5];
  __shared__ float  lmax[4];
  __shared__ int    lidx[4];
  const int wave = t >> 6, lane = t & 63;

  if (bid < DIV_BLOCKS) {
    // ---- per-(b,pos) max / second-max over r  ->  A,B,C block sums ----
    const unsigned gid = bid * 256u + t;
    const unsigned b = gid / QPP;
    const unsigned q = gid - b * QPP;
    const float4* base = reinterpret_cast<const float4*>(feat + (size_t)b * NR * WHD) + q;

    float v1[4], v2[4], f2m[4], cp[4];
#pragma unroll
    for (int c = 0; c < 4; ++c) { v1[c] = -INFINITY; v2[c] = -INFINITY; f2m[c] = 0.f; cp[c] = 0.f; }

#pragma unroll 4
    for (int r = 0; r < NR; ++r) {
      float4 v = base[(size_t)r * QPP];
      float vv[4] = {v.x, v.y, v.z, v.w};
#pragma unroll
      for (int c = 0; c < 4; ++c) {
        float f = vv[c], f2 = f * f;
        cp[c] += f2;
        if (f > v1[c]) { v2[c] = v1[c]; v1[c] = f; f2m[c] = f2; }  // first-index tie-break
        else if (f > v2[c]) { v2[c] = f; }
      }
    }

    float A = 0.f, Bs = 0.f, C = 0.f;
#pragma unroll
    for (int c = 0; c < 4; ++c) {
      float rest = cp[c] - f2m[c];
      A  += v1[c] * v1[c] * rest + v2[c] * v2[c] * f2m[c];
      Bs += v1[c] * rest + v2[c] * f2m[c];
      C  += cp[c];
    }

    double dA = A, dB = Bs, dC = C;
#pragma unroll
    for (int off = 32; off > 0; off >>= 1) {
      dA += __shfl_down(dA, off);
      dB += __shfl_down(dB, off);
      dC += __shfl_down(dC, off);
    }
    if (lane == 0) { ls[wave][0] = dA; ls[wave][1] = dB; ls[wave][2] = dC; }
    __syncthreads();
    if (t == 0) {
      double a = 0, bb = 0, cc = 0;
#pragma unroll
      for (int w = 0; w < 4; ++w) { a += ls[w][0]; bb += ls[w][1]; cc += ls[w][2]; }
      blk[bid * 3 + 0] = a;
      blk[bid * 3 + 1] = bb;
      blk[bid * 3 + 2] = cc;
    }
  } else {
    // ---- per-(plane,sub) moments + argmax ----
    const int pb = bid - DIV_BLOCKS;
    const int plane = pb / PLANE_SUBS;
    const int sub = pb - plane * PLANE_SUBS;
    const float4* f4 = reinterpret_cast<const float4*>(feat + (size_t)plane * WHD);

    float maxv = -INFINITY; int maxi = 0;
    float s0 = 0.f, sx = 0.f, sy = 0.f, sii = 0.f, ssum = 0.f;

    const int q0 = sub * QSUB;
#pragma unroll
    for (int it = 0; it < 9; ++it) {          // QSUB/256 = 9
      int q = q0 + it * 256 + t;
      float4 v = f4[q];
      float vv[4] = {v.x, v.y, v.z, v.w};
      int p0 = q * 4;
#pragma unroll
      for (int c = 0; c < 4; ++c) {
        float f = vv[c];
        int p = p0 + c;
        int i = p / HD;
        int rem = p - i * HD;
        int j = rem / W48;
        float f2 = f * f;
        float fi = (float)i, fj = (float)j;
        s0  += f2;
        sx  += f2 * fi;
        sy  += f2 * fj;
        sii += f2 * (fi * fi + fj * fj);
        ssum += f;
        if (f > maxv) { maxv = f; maxi = p; }   // strict > : first-index tie-break
      }
    }

    double d0 = s0, d1 = sx, d2 = sy, d3 = sii, d4 = ssum;
#pragma unroll
    for (int off = 32; off > 0; off >>= 1) {
      float ov = __shfl_down(maxv, off);
      int   oi = __shfl_down(maxi, off);
      if (ov > maxv || (ov == maxv && oi < maxi)) { maxv = ov; maxi = oi; }
      d0 += __shfl_down(d0, off);
      d1 += __shfl_down(d1, off);
      d2 += __shfl_down(d2, off);
      d3 += __shfl_down(d3, off);
      d4 += __shfl_down(d4, off);
    }

    if (lane == 0) {
      ls[wave][0] = d0; ls[wave][1] = d1; ls[wave][2] = d2;
      ls[wave][3] = d3; ls[wave][4] = d4;
      lmax[wave] = maxv; lidx[wave] = maxi;
    }
    __syncthreads();
    if (t == 0) {
      double a0=0, a1=0, a2=0, a3=0, a4=0;
      float mv = -INFINITY; int mi = 0;
#pragma unroll
      for (int w = 0; w < 4; ++w) {
        a0 += ls[w][0]; a1 += ls[w][1]; a2 += ls[w][2]; a3 += ls[w][3]; a4 += ls[w][4];
        if (lmax[w] > mv || (lmax[w] == mv && lidx[w] < mi)) { mv = lmax[w]; mi = lidx[w]; }
      }
      PlanePart r; r.s0=a0; r.sx=a1; r.sy=a2; r.sii=a3; r.ssum=a4; r.maxv=mv; r.maxi=mi;
      pp[pb] = r;
    }
  }
}

// ---------------------------- finalize ----------------------------
__global__ __launch_bounds__(256)
void k_final(const PlanePart* __restrict__ pp, const double* __restrict__ blk,
             float* __restrict__ out) {
  const int t = threadIdx.x;

  // combine 12 sub-partials for plane t
  double s0 = 0, sx = 0, sy = 0, sii = 0, ssum = 0;
  float mv = -INFINITY; int mi = 0x7fffffff;
#pragma unroll
  for (int s = 0; s < PLANE_SUBS; ++s) {
    PlanePart pr = pp[t * PLANE_SUBS + s];
    s0 += pr.s0; sx += pr.sx; sy += pr.sy; sii += pr.sii; ssum += pr.ssum;
    if (pr.maxv > mv || (pr.maxv == mv && pr.maxi < mi)) { mv = pr.maxv; mi = pr.maxi; }
  }

  int am = mi;
  int mx = am / HD;
  int rem = am - mx * HD;
  int my = rem / W48;
  int mz = rem - my * W48;
  double dmx = mx, dmy = my, dmz = mz;
  // sum_k (mz-k)^2 for k=0..47 = 48*mz^2 - 2256*mz + 35720 ; times W*H=2304
  double dis = (dmx*dmx + dmy*dmy) * s0 - 2.0*dmx*sx - 2.0*dmy*sy + sii
             + 2304.0 * (48.0*dmz*dmz - 2256.0*dmz + 35720.0);

  double A = 0, Bs = 0, C = 0;
  for (int idx = t; idx < DIV_BLOCKS; idx += 256) {
    A  += blk[idx * 3 + 0];
    Bs += blk[idx * 3 + 1];
    C  += blk[idx * 3 + 2];
  }

#pragma unroll
  for (int off = 32; off > 0; off >>= 1) {
    dis  += __shfl_down(dis, off);
    ssum += __shfl_down(ssum, off);
    A    += __shfl_down(A, off);
    Bs   += __shfl_down(Bs, off);
    C    += __shfl_down(C, off);
  }
  __shared__ double ls[4][5];
  int wave = t >> 6, lane = t & 63;
  if (lane == 0) {
    ls[wave][0] = dis; ls[wave][1] = ssum; ls[wave][2] = A; ls[wave][3] = Bs; ls[wave][4] = C;
  }
  __syncthreads();
  if (t == 0) {
    double td = 0, ts = 0, tA = 0, tB = 0, tC = 0;
#pragma unroll
    for (int w = 0; w < 4; ++w) {
      td += ls[w][0]; ts += ls[w][1]; tA += ls[w][2]; tB += ls[w][3]; tC += ls[w][4];
    }
    double mgr = ts / NTOT;
    out[0] = (float)(td / NTOT);
    out[1] = (float)((tA - 2.0 * mgr * tB + mgr * mgr * tC) / NTOT);
  }
}

extern "C" void kernel_launch(void* const* d_in, const int* in_sizes, int n_in,
                              void* d_out, int out_size, void* d_ws, size_t ws_size,
                              hipStream_t stream) {
  // inputs: [0]=backbone_feature (unused), [1]=grouping_result (unused), [2]=feature
  const float* feat = (const float*)d_in[2];
  float* out = (float*)d_out;

  PlanePart* pp = (PlanePart*)d_ws;                                    // 3072*48 = 147456 B
  double* blk = (double*)((char*)d_ws + sizeof(PlanePart) * PLANE_BLOCKS); // 864*3*8 = 20736 B

  k_main<<<DIV_BLOCKS + PLANE_BLOCKS, 256, 0, stream>>>(feat, pp, blk);
  k_final<<<1, 256, 0, stream>>>(pp, blk, out);
}

// Round 3
// 43.632 us; speedup vs baseline: 1.6283x; 1.1001x over previous
//
#include <hip/hip_runtime.h>
#include <math.h>

#define W48 48
#define HD 2304
#define WHD 110592
#define NR 32
#define NB 8
#define QPP 27648            // float4 groups per (b,r) plane
#define CHUNKS 108           // QPP / 256
#define MAIN_BLOCKS 864      // NB * CHUNKS
#define PARTS 432            // CHUNKS * 4 waves -> partials per plane
#define NTOT 28311552.0

struct PPart { float s0, sx, sy; unsigned int fkey; unsigned int idx; }; // 20 B

// order-preserving float -> uint key (larger float => larger key)
__device__ __forceinline__ unsigned fkey_of(float f) {
  unsigned u = __float_as_uint(f);
  return (u & 0x80000000u) ? ~u : (u | 0x80000000u);
}

// DPP full-wave (64-lane) reductions; result valid in lane 63. Pure VALU.
__device__ __forceinline__ float wave_red_add(float x) {
  int s;
  s = __builtin_amdgcn_update_dpp(0, __float_as_int(x), 0x111, 0xf, 0xf, true); x += __int_as_float(s);
  s = __builtin_amdgcn_update_dpp(0, __float_as_int(x), 0x112, 0xf, 0xf, true); x += __int_as_float(s);
  s = __builtin_amdgcn_update_dpp(0, __float_as_int(x), 0x114, 0xf, 0xf, true); x += __int_as_float(s);
  s = __builtin_amdgcn_update_dpp(0, __float_as_int(x), 0x118, 0xf, 0xf, true); x += __int_as_float(s);
  s = __builtin_amdgcn_update_dpp(0, __float_as_int(x), 0x142, 0xa, 0xf, true); x += __int_as_float(s);
  s = __builtin_amdgcn_update_dpp(0, __float_as_int(x), 0x143, 0xc, 0xf, true); x += __int_as_float(s);
  return x;
}
__device__ __forceinline__ unsigned wave_red_umax(unsigned x) {
  int s; unsigned u;
  s = __builtin_amdgcn_update_dpp(0, (int)x, 0x111, 0xf, 0xf, true); u = (unsigned)s; x = x > u ? x : u;
  s = __builtin_amdgcn_update_dpp(0, (int)x, 0x112, 0xf, 0xf, true); u = (unsigned)s; x = x > u ? x : u;
  s = __builtin_amdgcn_update_dpp(0, (int)x, 0x114, 0xf, 0xf, true); u = (unsigned)s; x = x > u ? x : u;
  s = __builtin_amdgcn_update_dpp(0, (int)x, 0x118, 0xf, 0xf, true); u = (unsigned)s; x = x > u ? x : u;
  s = __builtin_amdgcn_update_dpp(0, (int)x, 0x142, 0xa, 0xf, true); u = (unsigned)s; x = x > u ? x : u;
  s = __builtin_amdgcn_update_dpp(0, (int)x, 0x143, 0xc, 0xf, true); u = (unsigned)s; x = x > u ? x : u;
  return x;
}
__device__ __forceinline__ unsigned wave_red_umin(unsigned x) {
  int s; unsigned u;
  s = __builtin_amdgcn_update_dpp(-1, (int)x, 0x111, 0xf, 0xf, false); u = (unsigned)s; x = x < u ? x : u;
  s = __builtin_amdgcn_update_dpp(-1, (int)x, 0x112, 0xf, 0xf, false); u = (unsigned)s; x = x < u ? x : u;
  s = __builtin_amdgcn_update_dpp(-1, (int)x, 0x114, 0xf, 0xf, false); u = (unsigned)s; x = x < u ? x : u;
  s = __builtin_amdgcn_update_dpp(-1, (int)x, 0x118, 0xf, 0xf, false); u = (unsigned)s; x = x < u ? x : u;
  s = __builtin_amdgcn_update_dpp(-1, (int)x, 0x142, 0xa, 0xf, false); u = (unsigned)s; x = x < u ? x : u;
  s = __builtin_amdgcn_update_dpp(-1, (int)x, 0x143, 0xc, 0xf, false); u = (unsigned)s; x = x < u ? x : u;
  return x;
}

// ------------- single-pass fused kernel: div state in regs, per-r DPP reduce -------------
__global__ __launch_bounds__(256)
void k_main(const float* __restrict__ feat, PPart* __restrict__ pp,
            double* __restrict__ blk) {
  const int bid = blockIdx.x;
  const int t = threadIdx.x;
  const int b = bid / CHUNKS;
  const int chunk = bid - b * CHUNKS;
  const int qbase = chunk * 256 + t;
  const float4* gbase = reinterpret_cast<const float4*>(feat) + (size_t)b * (NR * QPP) + qbase;

  const int p0 = qbase * 4;
  const int i = p0 / HD;
  const int j = (p0 / W48) % W48;   // i,j constant over the 4 elems (4 | 48)
  const float fi = (float)i, fj = (float)j;
  const float rr = fi * fi + fj * fj;

  const int wave = t >> 6, lane = t & 63;

  float v1[4], v2[4], cp[4];
#pragma unroll
  for (int c = 0; c < 4; ++c) { v1[c] = -INFINITY; v2[c] = -INFINITY; cp[c] = 0.f; }
  float ssum = 0.f, sii = 0.f;

  float4 b0 = gbase[0];
  float4 b1 = gbase[QPP];

#pragma unroll 2
  for (int r = 0; r < NR; ++r) {
    float4 v = b0;
    b0 = b1;
    if (r < NR - 2) b1 = gbase[(size_t)(r + 2) * QPP];

    float vv[4] = {v.x, v.y, v.z, v.w};
    float s0t = 0.f;
#pragma unroll
    for (int c = 0; c < 4; ++c) {
      float f = vv[c];
      float f2 = f * f;
      s0t += f2;
      cp[c] += f2;
      ssum += f;
      float nv2 = fmaxf(f, v2[c]);
      v2[c] = (f > v1[c]) ? v1[c] : nv2;   // top-2 insert
      v1[c] = fmaxf(v1[c], f);
    }
    float mv = vv[0]; int mc = 0;
#pragma unroll
    for (int c = 1; c < 4; ++c) { if (vv[c] > mv) { mv = vv[c]; mc = c; } }  // first-index

    sii += s0t * rr;                        // global term, no per-r reduce needed
    float rsx = wave_red_add(s0t * fi);
    float rsy = wave_red_add(s0t * fj);
    float rs0 = wave_red_add(s0t);
    unsigned key = fkey_of(mv);
    unsigned wmax = wave_red_umax(key);
    wmax = (unsigned)__builtin_amdgcn_readlane((int)wmax, 63);
    unsigned cand = (key == wmax) ? (unsigned)(p0 + mc) : 0xffffffffu;
    unsigned widx = wave_red_umin(cand);    // exact first-index tie-break

    if (lane == 63) {
      PPart o; o.s0 = rs0; o.sx = rsx; o.sy = rsy; o.fkey = wmax; o.idx = widx;
      pp[((size_t)(b * NR + r) * CHUNKS + chunk) * 4 + wave] = o;
    }
  }

  // ---- div epilogue (note f2@argmax == v1^2) + global sums ----
  float A = 0.f, Bs = 0.f, C = 0.f;
#pragma unroll
  for (int c = 0; c < 4; ++c) {
    float m1 = v1[c];
    float m1sq = m1 * m1;
    float rest = cp[c] - m1sq;
    A  += m1sq * rest + v2[c] * v2[c] * m1sq;
    Bs += m1 * rest + v2[c] * m1sq;
    C  += cp[c];
  }
  double dA = A, dB = Bs, dC = C, dS = ssum, dI = sii;
#pragma unroll
  for (int off = 32; off; off >>= 1) {
    dA += __shfl_down(dA, off);
    dB += __shfl_down(dB, off);
    dC += __shfl_down(dC, off);
    dS += __shfl_down(dS, off);
    dI += __shfl_down(dI, off);
  }
  __shared__ double ld[4][5];
  if (lane == 0) { ld[wave][0]=dA; ld[wave][1]=dB; ld[wave][2]=dC; ld[wave][3]=dS; ld[wave][4]=dI; }
  __syncthreads();
  if (t == 0) {
    double a=0, bb=0, cc=0, ss=0, si=0;
#pragma unroll
    for (int w = 0; w < 4; ++w) { a+=ld[w][0]; bb+=ld[w][1]; cc+=ld[w][2]; ss+=ld[w][3]; si+=ld[w][4]; }
    blk[(size_t)bid*5+0]=a; blk[(size_t)bid*5+1]=bb; blk[(size_t)bid*5+2]=cc;
    blk[(size_t)bid*5+3]=ss; blk[(size_t)bid*5+4]=si;
  }
}

// ------------- stage 2: combine 432 partials per plane -> per-plane dis term -------------
__global__ __launch_bounds__(512)
void k_planes(const PPart* __restrict__ pp, double* __restrict__ planeDis) {
  const int p = blockIdx.x;
  const int t = threadIdx.x;
  double s0 = 0, sx = 0, sy = 0;
  unsigned fkey = 0, idx = 0xffffffffu;
  if (t < PARTS) {
    PPart v = pp[(size_t)p * PARTS + t];
    s0 = v.s0; sx = v.sx; sy = v.sy; fkey = v.fkey; idx = v.idx;
  }
#pragma unroll
  for (int off = 32; off; off >>= 1) {
    s0 += __shfl_down(s0, off);
    sx += __shfl_down(sx, off);
    sy += __shfl_down(sy, off);
    unsigned ok = __shfl_down(fkey, off);
    unsigned oi = __shfl_down(idx, off);
    if (ok > fkey || (ok == fkey && oi < idx)) { fkey = ok; idx = oi; }
  }
  __shared__ double ls[8][3];
  __shared__ unsigned lk[8][2];
  const int wave = t >> 6, lane = t & 63;
  if (lane == 0) { ls[wave][0]=s0; ls[wave][1]=sx; ls[wave][2]=sy; lk[wave][0]=fkey; lk[wave][1]=idx; }
  __syncthreads();
  if (t == 0) {
    double a0=0, a1=0, a2=0; unsigned bk=0, bi=0xffffffffu;
#pragma unroll
    for (int w = 0; w < 8; ++w) {
      a0 += ls[w][0]; a1 += ls[w][1]; a2 += ls[w][2];
      if (lk[w][0] > bk || (lk[w][0]==bk && lk[w][1] < bi)) { bk = lk[w][0]; bi = lk[w][1]; }
    }
    int am = (int)bi;
    int mx = am / HD;
    int rem = am - mx * HD;
    int my = rem / W48;
    int mz = rem - my * W48;
    double dmx = mx, dmy = my, dmz = mz;
    // sum_k (mz-k)^2, k=0..47 = 48 mz^2 - 2256 mz + 35720 ; times W*H=2304
    planeDis[p] = (dmx*dmx + dmy*dmy) * a0 - 2.0*dmx*a1 - 2.0*dmy*a2
                + 2304.0 * (48.0*dmz*dmz - 2256.0*dmz + 35720.0);
  }
}

// ------------- stage 3: final scalars -------------
__global__ __launch_bounds__(256)
void k_fin(const double* __restrict__ planeDis, const double* __restrict__ blk,
           float* __restrict__ out) {
  const int t = threadIdx.x;
  double dis = planeDis[t];     // exactly 256 planes
  double A = 0, B = 0, C = 0, S = 0, SII = 0;
  for (int i = t; i < MAIN_BLOCKS; i += 256) {
    A   += blk[(size_t)i*5+0];
    B   += blk[(size_t)i*5+1];
    C   += blk[(size_t)i*5+2];
    S   += blk[(size_t)i*5+3];
    SII += blk[(size_t)i*5+4];
  }
#pragma unroll
  for (int off = 32; off; off >>= 1) {
    dis += __shfl_down(dis, off);
    A   += __shfl_down(A, off);
    B   += __shfl_down(B, off);
    C   += __shfl_down(C, off);
    S   += __shfl_down(S, off);
    SII += __shfl_down(SII, off);
  }
  __shared__ double ls[4][6];
  const int wave = t >> 6, lane = t & 63;
  if (lane == 0) {
    ls[wave][0]=dis; ls[wave][1]=A; ls[wave][2]=B; ls[wave][3]=C; ls[wave][4]=S; ls[wave][5]=SII;
  }
  __syncthreads();
  if (t == 0) {
    double td=0, tA=0, tB=0, tC=0, tS=0, tI=0;
#pragma unroll
    for (int w = 0; w < 4; ++w) {
      td+=ls[w][0]; tA+=ls[w][1]; tB+=ls[w][2]; tC+=ls[w][3]; tS+=ls[w][4]; tI+=ls[w][5];
    }
    double mgr = tS / NTOT;
    out[0] = (float)((td + tI) / NTOT);
    out[1] = (float)((tA - 2.0*mgr*tB + mgr*mgr*tC) / NTOT);
  }
}

extern "C" void kernel_launch(void* const* d_in, const int* in_sizes, int n_in,
                              void* d_out, int out_size, void* d_ws, size_t ws_size,
                              hipStream_t stream) {
  // inputs: [0]=backbone_feature (unused), [1]=grouping_result (unused), [2]=feature
  const float* feat = (const float*)d_in[2];
  float* out = (float*)d_out;

  PPart* pp = (PPart*)d_ws;                                      // 110592*20 = 2211840 B
  double* blk = (double*)((char*)d_ws + 2211840);                // 864*5*8 = 34560 B
  double* planeDis = (double*)((char*)d_ws + 2211840 + 34560);   // 256*8 = 2048 B

  k_main<<<MAIN_BLOCKS, 256, 0, stream>>>(feat, pp, blk);
  k_planes<<<256, 512, 0, stream>>>(pp, planeDis);
  k_fin<<<1, 256, 0, stream>>>(planeDis, blk, out);
}